// Round 10
// baseline (1378.944 us; speedup 1.0000x reference)
//
#include <hip/hip_runtime.h>
#include <stdint.h>

// ============================================================================
// Encoder (6-layer rel-pos transformer), MI355X. f32 in/out, bf16 internals.
// R15: flash_attn barrier-free redesign. R14 counters showed the structural
// cap: 3072 waves total = 12 waves/CU for ANY blocking, and per-iter cost is
// staging + 2 barrier drains. Key insight: each lane's MFMA K/V fragment is
// 16 CONTIGUOUS bytes in global memory -> load operands directly from L2,
// delete K/V LDS, staging loops, and ALL per-iteration __syncthreads. Blocks
// are now 1 wave / 64 threads (3072 blocks, XCD-swizzled); each wave
// free-runs, hiding its own L2 latency. LDS = Pl (2KB, same-wave) + bandk +
// maskW. Same HBM traffic; L2 ~20 TB/s < 35 ceiling. gemm_bt4 untouched.
// ============================================================================

typedef unsigned short u16;
typedef __attribute__((ext_vector_type(8))) __bf16 bf16x8;
typedef __attribute__((ext_vector_type(4))) float f32x4;

#define B_ 8
#define T_ 768
#define C_ 512
#define F_ 2048
#define LOG2E 1.4426950408889634f

__device__ __forceinline__ float b2f(u16 u) {
    union { float f; uint32_t i; } x; x.i = ((uint32_t)u) << 16; return x.f;
}
__device__ __forceinline__ u16 f2b(float f) {
    union { float f; uint32_t i; } x; x.f = f;
    return (u16)((x.i + 0x7fffu + ((x.i >> 16) & 1u)) >> 16);  // RNE
}

// ---------------------------------------------------------------------------
// gemm_bt4 (R10-verified, DO NOT pipeline — reg-staged dbuf spills
// unconditionally here, R7+R11 evidence): 64x64 block, 4 waves, wave=32x32.
// ---------------------------------------------------------------------------
template <int EPI>
__global__ __launch_bounds__(256) void gemm_bt4(
    const u16* __restrict__ A, int aStride,
    const u16* __restrict__ Bt, int bStride,
    const float* __restrict__ bias,
    u16* __restrict__ out, int oStride, int K, float epiScale)
{
    const int tid = threadIdx.x;
    const int wave = tid >> 6, lane = tid & 63;
    const int wm = wave & 1, wn = wave >> 1;
    const int quad = lane >> 4, l16 = lane & 15;
    const int m0 = blockIdx.x * 64;
    const int n0 = blockIdx.y * 64;

    __shared__ u16 As[64 * 64];
    __shared__ u16 Bs[64 * 64];

    const f32x4 vzero = {0.f, 0.f, 0.f, 0.f};
    f32x4 acc[2][2];
#pragma unroll
    for (int i = 0; i < 2; ++i)
#pragma unroll
        for (int j = 0; j < 2; ++j) acc[i][j] = vzero;

    for (int k0 = 0; k0 < K; k0 += 64) {
#pragma unroll
        for (int i = 0; i < 2; ++i) {
            int c = tid + i * 256;
            int row = c >> 3, pc = c & 7, lc = pc ^ (row & 7);
            *(uint4*)&As[c * 8] =
                *(const uint4*)(A + (long long)(m0 + row) * aStride + (k0 + lc * 8));
            *(uint4*)&Bs[c * 8] =
                *(const uint4*)(Bt + (long long)(n0 + row) * bStride + (k0 + lc * 8));
        }
        __syncthreads();
        __builtin_amdgcn_s_setprio(1);
#pragma unroll
        for (int ks = 0; ks < 2; ++ks) {
            bf16x8 af[2], bfr[2];
#pragma unroll
            for (int mi = 0; mi < 2; ++mi) {
                int row = wm * 32 + mi * 16 + l16;
                int pc = ((ks << 2) | quad) ^ (row & 7);
                af[mi] = *(const bf16x8*)&As[row * 64 + pc * 8];
            }
#pragma unroll
            for (int ni = 0; ni < 2; ++ni) {
                int row = wn * 32 + ni * 16 + l16;
                int pc = ((ks << 2) | quad) ^ (row & 7);
                bfr[ni] = *(const bf16x8*)&Bs[row * 64 + pc * 8];
            }
#pragma unroll
            for (int mi = 0; mi < 2; ++mi)
#pragma unroll
                for (int ni = 0; ni < 2; ++ni)
                    acc[mi][ni] = __builtin_amdgcn_mfma_f32_16x16x32_bf16(
                        bfr[ni], af[mi], acc[mi][ni], 0, 0, 0);
        }
        __builtin_amdgcn_s_setprio(0);
        __syncthreads();
    }

#pragma unroll
    for (int mi = 0; mi < 2; ++mi) {
        int row = m0 + wm * 32 + mi * 16 + l16;
#pragma unroll
        for (int ni = 0; ni < 2; ++ni) {
            int colb = n0 + wn * 32 + ni * 16 + quad * 4;
            u16 pk[4];
#pragma unroll
            for (int r = 0; r < 4; ++r) {
                float v = acc[mi][ni][r] + bias[colb + r];
                if (EPI == 1) v = v > 0.f ? v : 0.f;
                if (EPI == 3) { if (colb + r < 512) v *= epiScale; }
                pk[r] = f2b(v);
            }
            uint2 p;
            p.x = (uint32_t)pk[0] | ((uint32_t)pk[1] << 16);
            p.y = (uint32_t)pk[2] | ((uint32_t)pk[3] << 16);
            *(uint2*)(out + (long long)row * oStride + colb) = p;
        }
    }
}

// ---------------------------------------------------------------------------
// bandg[(t*8 + h)*9 + e] = q~[t,h,:] . erk[e,:]  (q pre-scaled by log2e/8)
// ---------------------------------------------------------------------------
__global__ __launch_bounds__(256) void bandg_k(
    const u16* __restrict__ qkv, const float* __restrict__ erk,
    float* __restrict__ bandg)
{
    __shared__ float erkS[576];
    const int tid = threadIdx.x;
    for (int idx = tid; idx < 576; idx += 256) erkS[idx] = erk[idx];
    __syncthreads();
    const int gid = blockIdx.x * 256 + tid;       // 49152
    const int row = gid >> 3, h = gid & 7;
    const u16* q = qkv + (long long)row * 1536 + h * 64;
    float acc[9];
#pragma unroll
    for (int e = 0; e < 9; ++e) acc[e] = 0.f;
#pragma unroll
    for (int c = 0; c < 8; ++c) {
        uint4 d4 = *(const uint4*)(q + c * 8);
        const uint32_t dw[4] = {d4.x, d4.y, d4.z, d4.w};
#pragma unroll
        for (int j = 0; j < 8; ++j) {
            u16 uu = (u16)((dw[j >> 1] >> ((j & 1) * 16)) & 0xffff);
            float qv = b2f(uu);
            int d = c * 8 + j;
#pragma unroll
            for (int e = 0; e < 9; ++e) acc[e] += qv * erkS[e * 64 + d];
        }
    }
    float* o = bandg + (long long)gid * 9;
#pragma unroll
    for (int e = 0; e < 9; ++e) o[e] = acc[e];
}

// ---------------------------------------------------------------------------
// Flash attention R15: 1 wave / 64 threads / 16 q-rows per block; K/V MFMA
// fragments loaded DIRECTLY from global (16B contiguous per lane, L2-hot);
// no K/V LDS, no per-iteration barriers. LDS: Pl 2KB + bandk + maskW.
// Grid 48x64 = 3072 blocks, XCD-swizzled (3072 % 8 == 0, bijective).
// ---------------------------------------------------------------------------
__global__ __launch_bounds__(64) void flash_attn(
    const u16* __restrict__ qkv, const u16* __restrict__ vt,
    const float* __restrict__ mask, const float* __restrict__ bandg,
    const float* __restrict__ erv, u16* __restrict__ outb)
{
    const int lane = threadIdx.x;          // 0..63
    const int quad = lane >> 4, l16 = lane & 15;
    const int orig = blockIdx.y * 48 + blockIdx.x;
    const int swz = (orig & 7) * 384 + (orig >> 3);
    const int qt = swz % 48, bh = swz / 48;
    const int b = bh >> 3, h = bh & 7;
    const int q0 = qt * 16;

    __shared__ u16 Pl[16 * 64];        // 2 KB, single-wave
    __shared__ float bandk[16][10];
    __shared__ float maskW[64];

    for (int idx = lane; idx < 144; idx += 64) {
        int r = idx / 9, e = idx - r * 9;
        bandk[r][e] = bandg[((long long)(b * T_ + q0 + r) * 8 + h) * 9 + e];
    }
    __syncthreads();   // once; single wave, cheap

    const int i_row = q0 + l16;
    const float mi = mask[b * T_ + i_row];
    const bool row_masked_any = (__ballot(mi == 0.f) != 0ull);  // wave-uniform

    // Q fragments direct from global, hoisted to registers
    const u16* qrow = qkv + (long long)(b * T_ + i_row) * 1536 + h * 64;
    bf16x8 qf[2];
#pragma unroll
    for (int ks = 0; ks < 2; ++ks)
        qf[ks] = *(const bf16x8*)(qrow + ks * 32 + quad * 8);

    // per-lane fragment row bases: r = ni*16 + l16
    const u16* kbase[4];
    const u16* vbase[4];
#pragma unroll
    for (int ni = 0; ni < 4; ++ni) {
        int r = ni * 16 + l16;
        kbase[ni] = qkv + ((long long)(b * T_) + r) * 1536 + 512 + h * 64;
        vbase[ni] = vt + ((long long)bh * 64 + r) * T_;
    }

    float m_run = -1e30f, l_run = 0.f;
    const f32x4 vzero = {0.f, 0.f, 0.f, 0.f};
    f32x4 vacc[4] = {vzero, vzero, vzero, vzero};
    float pb[3] = {0.f, 0.f, 0.f};

    for (int kt = 0; kt < 12; ++kt) {
        const float mval = mask[b * T_ + kt * 64 + lane];
        const bool tile_clean = (__ballot(mval == 0.f) == 0ull);
        const bool fast = tile_clean && !row_masked_any;        // wave-uniform
        const bool has_band = (kt * 64 <= q0 + 19) && (kt * 64 + 67 >= q0);
        const long long ktoff = (long long)kt * 64 * 1536;
        const int kcol = quad * 8;

        // S = Q @ K^T — K fragments straight from global (L2-hot)
        f32x4 sacc[4];
#pragma unroll
        for (int ni = 0; ni < 4; ++ni) sacc[ni] = vzero;
        __builtin_amdgcn_s_setprio(1);
#pragma unroll
        for (int ks = 0; ks < 2; ++ks)
#pragma unroll
            for (int ni = 0; ni < 4; ++ni) {
                bf16x8 kf = *(const bf16x8*)(kbase[ni] + ktoff + ks * 32 + kcol);
                sacc[ni] = __builtin_amdgcn_mfma_f32_16x16x32_bf16(kf, qf[ks], sacc[ni], 0, 0, 0);
            }
        __builtin_amdgcn_s_setprio(0);

        if (has_band) {
#pragma unroll
            for (int ni = 0; ni < 4; ++ni)
#pragma unroll
                for (int r = 0; r < 4; ++r) {
                    int jl = ni * 16 + quad * 4 + r;
                    int dlt = kt * 64 + jl - i_row;
                    if (dlt >= -4 && dlt <= 4)
                        sacc[ni][r] += bandk[l16][dlt + 4];
                }
        }
        if (!fast) {
            maskW[lane] = mval;   // same-wave LDS RAW — program-order safe
#pragma unroll
            for (int ni = 0; ni < 4; ++ni)
#pragma unroll
                for (int r = 0; r < 4; ++r) {
                    int jl = ni * 16 + quad * 4 + r;
                    if (mi * maskW[jl] == 0.f) sacc[ni][r] = -14427.0f;  // -1e4*log2e
                }
        }

        // row max: pairwise tree
        float mx;
        {
            float a0 = fmaxf(sacc[0][0], sacc[0][1]), a1 = fmaxf(sacc[0][2], sacc[0][3]);
            float b0 = fmaxf(sacc[1][0], sacc[1][1]), b1 = fmaxf(sacc[1][2], sacc[1][3]);
            float c0 = fmaxf(sacc[2][0], sacc[2][1]), c1 = fmaxf(sacc[2][2], sacc[2][3]);
            float d0 = fmaxf(sacc[3][0], sacc[3][1]), d1 = fmaxf(sacc[3][2], sacc[3][3]);
            float t0 = fmaxf(fmaxf(a0, a1), fmaxf(b0, b1));
            float t1 = fmaxf(fmaxf(c0, c1), fmaxf(d0, d1));
            mx = fmaxf(t0, t1);
        }
        mx = fmaxf(mx, __shfl_xor(mx, 16));
        mx = fmaxf(mx, __shfl_xor(mx, 32));
        const float m_new = fmaxf(m_run, mx);
        const float alpha = exp2f(m_run - m_new);
        m_run = m_new;
        l_run *= alpha;
#pragma unroll
        for (int ni = 0; ni < 4; ++ni) vacc[ni] = vacc[ni] * alpha;
#pragma unroll
        for (int k = 0; k < 3; ++k) pb[k] *= alpha;

        // exp2 + native-pack P tile (same-wave LDS, no barrier)
        float lsum = 0.f;
#pragma unroll
        for (int ni = 0; ni < 4; ++ni) {
            float u0 = exp2f(sacc[ni][0] - m_new);
            float u1 = exp2f(sacc[ni][1] - m_new);
            float u2 = exp2f(sacc[ni][2] - m_new);
            float u3 = exp2f(sacc[ni][3] - m_new);
            lsum += (u0 + u1) + (u2 + u3);
            union { __bf16 hh[2]; uint32_t u; } cA, cB;
            cA.hh[0] = (__bf16)u0; cA.hh[1] = (__bf16)u1;
            cB.hh[0] = (__bf16)u2; cB.hh[1] = (__bf16)u3;
            int c0 = ni * 16 + quad * 4;
            int phys = (((c0 >> 3) ^ (l16 & 7)) << 3) + (c0 & 7);
            uint2 p; p.x = cA.u; p.y = cB.u;
            *(uint2*)&Pl[l16 * 64 + phys] = p;
        }
        l_run += lsum;

        if (has_band) {
#pragma unroll
            for (int k = 0; k < 3; ++k) {
                int e = quad * 3 + k;
                if (e < 9) {
                    int jl = i_row + e - 4 - kt * 64;
                    if (jl >= 0 && jl < 64) {
                        int phys = (((jl >> 3) ^ (l16 & 7)) << 3) + (jl & 7);
                        pb[k] += b2f(Pl[l16 * 64 + phys]);
                    }
                }
            }
        }

        // PV: V^T fragments straight from global (L2-hot)
        __builtin_amdgcn_s_setprio(1);
#pragma unroll
        for (int ks = 0; ks < 2; ++ks) {
            int pcc = ((ks << 2) | quad) ^ (l16 & 7);
            bf16x8 pf = *(const bf16x8*)&Pl[l16 * 64 + pcc * 8];
#pragma unroll
            for (int ni = 0; ni < 4; ++ni) {
                bf16x8 vf = *(const bf16x8*)(vbase[ni] + kt * 64 + ks * 32 + kcol);
                vacc[ni] = __builtin_amdgcn_mfma_f32_16x16x32_bf16(vf, pf, vacc[ni], 0, 0, 0);
            }
        }
        __builtin_amdgcn_s_setprio(0);
    }

    l_run += __shfl_xor(l_run, 16);
    l_run += __shfl_xor(l_run, 32);
    const float rinv = 1.f / l_run;

    float pband[9];
#pragma unroll
    for (int e = 0; e < 9; ++e) {
        float val = (quad == e / 3) ? pb[e % 3] : 0.f;
        val += __shfl_xor(val, 16);
        val += __shfl_xor(val, 32);
        pband[e] = val * rinv;
    }

    u16* orow = outb + (long long)(b * T_ + i_row) * C_ + h * 64;
#pragma unroll
    for (int ni = 0; ni < 4; ++ni) {
        u16 pk[4];
#pragma unroll
        for (int r = 0; r < 4; ++r) {
            int d = ni * 16 + quad * 4 + r;
            float v = vacc[ni][r] * rinv;
#pragma unroll
            for (int e = 0; e < 9; ++e) v += pband[e] * erv[e * 64 + d];
            pk[r] = f2b(v);
        }
        uint2 p;
        p.x = (uint32_t)pk[0] | ((uint32_t)pk[1] << 16);
        p.y = (uint32_t)pk[2] | ((uint32_t)pk[3] << 16);
        *(uint2*)(orow + ni * 16 + quad * 4) = p;
    }
}

// ---------------------------------------------------------------------------
// One-time weight transposes (f32 -> bf16), batched over layers.
// ---------------------------------------------------------------------------
__global__ void transpose_qkvo(const float* __restrict__ Wq, const float* __restrict__ Wk,
                               const float* __restrict__ Wv, const float* __restrict__ Wo,
                               u16* __restrict__ wqkvT, u16* __restrict__ woT)
{
    __shared__ u16 tile[32][33];
    const int z = blockIdx.z, l = z >> 2, which = z & 3;
    const float* src = (which == 0 ? Wq : which == 1 ? Wk : which == 2 ? Wv : Wo)
                       + (long long)l * 262144;
    u16* dst = (which == 3) ? woT + (long long)l * 262144
                            : wqkvT + (long long)l * 786432 + which * 262144;
    const int r0 = blockIdx.y * 32, c0 = blockIdx.x * 32;
    const int tx = threadIdx.x, ty = threadIdx.y;
#pragma unroll
    for (int i = 0; i < 32; i += 8)
        tile[ty + i][tx] = f2b(src[(long long)(r0 + ty + i) * 512 + (c0 + tx)]);
    __syncthreads();
#pragma unroll
    for (int i = 0; i < 32; i += 8)
        dst[(long long)(c0 + ty + i) * 512 + (r0 + tx)] = tile[tx][ty + i];
}

__global__ void transpose_f2bL(const float* __restrict__ src0, int sStride, long long sLayer,
                               u16* __restrict__ dst0, int dStride, long long dLayer)
{
    __shared__ u16 tile[32][33];
    const int l = blockIdx.z;
    const float* src = src0 + (long long)l * sLayer;
    u16* dst = dst0 + (long long)l * dLayer;
    const int r0 = blockIdx.y * 32, c0 = blockIdx.x * 32;
    const int tx = threadIdx.x, ty = threadIdx.y;
#pragma unroll
    for (int i = 0; i < 32; i += 8)
        tile[ty + i][tx] = f2b(src[(long long)(r0 + ty + i) * sStride + (c0 + tx)]);
    __syncthreads();
#pragma unroll
    for (int i = 0; i < 32; i += 8)
        dst[(long long)(c0 + ty + i) * dStride + (r0 + tx)] = tile[tx][ty + i];
}

__global__ void transpose_b(const u16* __restrict__ src, long long sB1, long long sB2, int sStride,
                            u16* __restrict__ dst, long long dB1, long long dB2, int dStride)
{
    __shared__ u16 tile[32][33];
    const int z = blockIdx.z, zb = z >> 3, zh = z & 7;
    src += (long long)zb * sB1 + (long long)zh * sB2;
    dst += (long long)zb * dB1 + (long long)zh * dB2;
    const int r0 = blockIdx.y * 32, c0 = blockIdx.x * 32;
    const int tx = threadIdx.x, ty = threadIdx.y;
#pragma unroll
    for (int i = 0; i < 32; i += 8)
        tile[ty + i][tx] = src[(long long)(r0 + ty + i) * sStride + (c0 + tx)];
    __syncthreads();
#pragma unroll
    for (int i = 0; i < 32; i += 8)
        dst[(long long)(c0 + ty + i) * dStride + (r0 + tx)] = tile[tx][ty + i];
}

__global__ void concat_bias(const float* __restrict__ bq, const float* __restrict__ bk,
                            const float* __restrict__ bv, float* __restrict__ dst)
{
    int i = blockIdx.x * 256 + threadIdx.x;
    int l = i / 1536, n = i - l * 1536;
    float v = (n < 512) ? bq[l * 512 + n]
             : (n < 1024 ? bk[l * 512 + (n - 512)] : bv[l * 512 + (n - 1024)]);
    dst[i] = v;
}

__global__ void mask_in(const float* __restrict__ x, const float* __restrict__ mask,
                        u16* __restrict__ out)
{
    int i4 = (blockIdx.x * 256 + threadIdx.x) * 4;
    float4 xv = *(const float4*)(x + i4);
    float m = mask[i4 >> 9];
    u16 pk[4] = {f2b(xv.x * m), f2b(xv.y * m), f2b(xv.z * m), f2b(xv.w * m)};
    uint2 p; p.x = (uint32_t)pk[0] | ((uint32_t)pk[1] << 16);
    p.y = (uint32_t)pk[2] | ((uint32_t)pk[3] << 16);
    *(uint2*)(out + i4) = p;
}

__global__ void mask_out(const u16* __restrict__ x, const float* __restrict__ mask,
                         float* __restrict__ out)
{
    int i4 = (blockIdx.x * 256 + threadIdx.x) * 4;
    uint2 p = *(const uint2*)(x + i4);
    float m = mask[i4 >> 9];
    float4 o;
    o.x = b2f((u16)(p.x & 0xffff)) * m;
    o.y = b2f((u16)(p.x >> 16)) * m;
    o.z = b2f((u16)(p.y & 0xffff)) * m;
    o.w = b2f((u16)(p.y >> 16)) * m;
    *(float4*)(out + i4) = o;
}

__global__ __launch_bounds__(256) void add_ln(
    const u16* __restrict__ x, const u16* __restrict__ y,
    const float* __restrict__ sc, const float* __restrict__ bi,
    u16* __restrict__ outx)
{
    const int wave = threadIdx.x >> 6, lane = threadIdx.x & 63;
    const long long r = (long long)blockIdx.x * 4 + wave;
    const u16* xr = x + r * C_;
    const u16* yr = y + r * C_;
    float v[8], s = 0.f;
#pragma unroll
    for (int it = 0; it < 2; ++it) {
        int j0 = it * 256 + lane * 4;
        uint2 px = *(const uint2*)(xr + j0);
        uint2 py = *(const uint2*)(yr + j0);
        v[it * 4 + 0] = b2f((u16)(px.x & 0xffff)) + b2f((u16)(py.x & 0xffff));
        v[it * 4 + 1] = b2f((u16)(px.x >> 16))    + b2f((u16)(py.x >> 16));
        v[it * 4 + 2] = b2f((u16)(px.y & 0xffff)) + b2f((u16)(py.y & 0xffff));
        v[it * 4 + 3] = b2f((u16)(px.y >> 16))    + b2f((u16)(py.y >> 16));
        s += v[it * 4 + 0] + v[it * 4 + 1] + v[it * 4 + 2] + v[it * 4 + 3];
    }
#pragma unroll
    for (int off = 32; off > 0; off >>= 1) s += __shfl_down(s, off);
    s = __shfl(s, 0);
    const float mean = s * (1.f / 512.f);
    float var = 0.f;
#pragma unroll
    for (int l = 0; l < 8; ++l) { float d = v[l] - mean; var += d * d; }
#pragma unroll
    for (int off = 32; off > 0; off >>= 1) var += __shfl_down(var, off);
    var = __shfl(var, 0);
    const float rs = rsqrtf(var * (1.f / 512.f) + 1e-6f);
    u16* orow = outx + r * C_;
#pragma unroll
    for (int it = 0; it < 2; ++it) {
        int j0 = it * 256 + lane * 4;
        float4 s4 = *(const float4*)(sc + j0);
        float4 b4 = *(const float4*)(bi + j0);
        u16 pk[4];
        pk[0] = f2b((v[it * 4 + 0] - mean) * rs * s4.x + b4.x);
        pk[1] = f2b((v[it * 4 + 1] - mean) * rs * s4.y + b4.y);
        pk[2] = f2b((v[it * 4 + 2] - mean) * rs * s4.z + b4.z);
        pk[3] = f2b((v[it * 4 + 3] - mean) * rs * s4.w + b4.w);
        uint2 p; p.x = (uint32_t)pk[0] | ((uint32_t)pk[1] << 16);
        p.y = (uint32_t)pk[2] | ((uint32_t)pk[3] << 16);
        *(uint2*)(orow + j0) = p;
    }
}

// ===========================================================================
extern "C" void kernel_launch(void* const* d_in, const int* in_sizes, int n_in,
                              void* d_out, int out_size, void* d_ws, size_t ws_size,
                              hipStream_t stream)
{
    const float* x    = (const float*)d_in[0];
    const float* mask = (const float*)d_in[1];
    const float* Wq   = (const float*)d_in[2];
    const float* bq   = (const float*)d_in[3];
    const float* Wk   = (const float*)d_in[4];
    const float* bk   = (const float*)d_in[5];
    const float* Wv   = (const float*)d_in[6];
    const float* bv   = (const float*)d_in[7];
    const float* Wo   = (const float*)d_in[8];
    const float* bo   = (const float*)d_in[9];
    const float* erk  = (const float*)d_in[10];
    const float* erv  = (const float*)d_in[11];
    const float* ln1s = (const float*)d_in[12];
    const float* ln1b = (const float*)d_in[13];
    const float* W1   = (const float*)d_in[14];
    const float* b1   = (const float*)d_in[15];
    const float* W2   = (const float*)d_in[16];
    const float* b2   = (const float*)d_in[17];
    const float* ln2s = (const float*)d_in[18];
    const float* ln2b = (const float*)d_in[19];
    float* out = (float*)d_out;
    u16* ws  = (u16*)d_ws;

    const long long CF = 512LL * 2048;
    const int M = B_ * T_;  // 6144

    // ws layout (u16 units). Total 51,234,816 u16 = 102.5 MB (<121.7 MB proven).
    u16* wqkvT   = ws;                      // [6][1536][512]
    u16* woT     = ws + 4718592;            // [6][512][512]
    u16* w1T     = ws + 6291456;            // [6][2048][512]
    u16* w2T     = ws + 12582912;           // [6][512][2048]
    float* bqkv  = (float*)(ws + 18874368); // [6][1536] f32
    u16* xb      = ws + 18892800;           // [M][512]
    u16* qkvb    = ws + 22038528;           // [M][1536]
    u16* vtb     = ws + 31475712;           // [64][64][768]; aliased as yb
    u16* attnb   = ws + 34621440;           // [M][512]
    u16* scr     = ws + 37767168;           // h1 [M][2048]
    float* bandg = (float*)(ws + 50350080); // [M][8][9] f32
    u16* yb      = vtb;

    const dim3 tb(32, 8);

    // --- one-time prologue ---
    transpose_qkvo<<<dim3(16, 16, 24), tb, 0, stream>>>(Wq, Wk, Wv, Wo, wqkvT, woT);
    transpose_f2bL<<<dim3(64, 16, 6), tb, 0, stream>>>(W1, 2048, CF, w1T, 512, 1048576);
    transpose_f2bL<<<dim3(16, 64, 6), tb, 0, stream>>>(W2, 512,  CF, w2T, 2048, 1048576);
    concat_bias<<<36, 256, 0, stream>>>(bq, bk, bv, bqkv);
    mask_in<<<(M * 512) / 1024, 256, 0, stream>>>(x, mask, xb);

    for (int l = 0; l < 6; ++l) {
        // QKV: [6144,512] @ [1536,512]^T; q *= log2e/8 in epilogue (cols<512)
        gemm_bt4<3><<<dim3(96, 24), 256, 0, stream>>>(
            xb, 512, wqkvT + (long long)l * 786432, 512, bqkv + l * 1536,
            qkvb, 1536, 512, 0.125f * LOG2E);
        // bandk table for this layer
        bandg_k<<<192, 256, 0, stream>>>(qkvb, erk + l * 576, bandg);
        // V^T per head: [64][768]
        transpose_b<<<dim3(2, 24, 64), tb, 0, stream>>>(
            qkvb + 1024, 768LL * 1536, 64, 1536,
            vtb, 8LL * 64 * 768, 64LL * 768, 768);
        // fused attention -> attnb (3072 blocks x 1 wave, barrier-free loop)
        flash_attn<<<dim3(48, 64), 64, 0, stream>>>(
            qkvb, vtb, mask, bandg, erv + l * 576, attnb);
        // O projection -> yb (=vtb, dead now)
        gemm_bt4<0><<<dim3(96, 8), 256, 0, stream>>>(
            attnb, 512, woT + (long long)l * 262144, 512, bo + l * 512,
            yb, 512, 512, 0.f);
        add_ln<<<1536, 256, 0, stream>>>(xb, yb, ln1s + l * 512, ln1b + l * 512, xb);
        // FFN1 (relu fused)
        gemm_bt4<1><<<dim3(96, 32), 256, 0, stream>>>(
            xb, 512, w1T + (long long)l * 1048576, 512, b1 + l * 2048,
            scr, 2048, 512, 0.f);
        // FFN2
        gemm_bt4<0><<<dim3(96, 8), 256, 0, stream>>>(
            scr, 2048, w2T + (long long)l * 1048576, 2048, b2 + l * 512,
            yb, 512, 2048, 0.f);
        add_ln<<<1536, 256, 0, stream>>>(xb, yb, ln2s + l * 512, ln2b + l * 512, xb);
    }

    mask_out<<<(M * 512) / 1024, 256, 0, stream>>>(xb, mask, out);
}

// Round 11
// 1008.036 us; speedup vs baseline: 1.3680x; 1.3680x over previous
//
#include <hip/hip_runtime.h>
#include <stdint.h>

// ============================================================================
// Encoder (6-layer rel-pos transformer), MI355X. f32 in/out, bf16 internals.
// R16: (1) flash_attn reverted to R14-exact (verified 46us; R15's direct-
// from-global refuted: VGPR 156, serial L2 latency into MFMA, 106us).
// (2) gemm_bt4 staging switched to __builtin_amdgcn_global_load_lds width=16
// INSIDE the unchanged two-barrier R10 structure — no pipelining. LDS dest =
// wave-uniform base + lane*16 (linear chunk layout), global src pre-swizzled
// column (m173 both-sides pattern); barrier's vmcnt(0) drain completes the
// DMA. Removes the VGPR round-trip + lgkm waits from staging.
// ============================================================================

typedef unsigned short u16;
typedef __attribute__((ext_vector_type(8))) __bf16 bf16x8;
typedef __attribute__((ext_vector_type(4))) float f32x4;

#define B_ 8
#define T_ 768
#define C_ 512
#define F_ 2048
#define LOG2E 1.4426950408889634f

__device__ __forceinline__ float b2f(u16 u) {
    union { float f; uint32_t i; } x; x.i = ((uint32_t)u) << 16; return x.f;
}
__device__ __forceinline__ u16 f2b(float f) {
    union { float f; uint32_t i; } x; x.f = f;
    return (u16)((x.i + 0x7fffu + ((x.i >> 16) & 1u)) >> 16);  // RNE
}

// Direct global->LDS DMA, 16B/lane. LDS dest must be wave-uniform (HW adds
// lane*16); global src is per-lane.
__device__ __forceinline__ void gload_lds16(const u16* g, u16* l) {
    __builtin_amdgcn_global_load_lds(
        (const __attribute__((address_space(1))) void*)(g),
        (__attribute__((address_space(3))) void*)(l), 16, 0, 0);
}

// ---------------------------------------------------------------------------
// gemm_bt4: 64x64 block, 256 threads, 4 waves (2x2), wave = 32x32 output.
// R10 two-barrier structure; staging now via global_load_lds (no staging
// VGPRs, no ds_write). Chunk c = tid + i*256 -> LDS byte c*16 (linear in
// lane within each wave's 64-chunk span); global column pre-swizzled.
// DO NOT pipeline (reg-staged dbuf spills unconditionally: R7+R11).
// ---------------------------------------------------------------------------
template <int EPI>
__global__ __launch_bounds__(256) void gemm_bt4(
    const u16* __restrict__ A, int aStride,
    const u16* __restrict__ Bt, int bStride,
    const float* __restrict__ bias,
    u16* __restrict__ out, int oStride, int K, float epiScale)
{
    const int tid = threadIdx.x;
    const int wave = tid >> 6, lane = tid & 63;
    const int wm = wave & 1, wn = wave >> 1;
    const int quad = lane >> 4, l16 = lane & 15;
    const int m0 = blockIdx.x * 64;
    const int n0 = blockIdx.y * 64;

    __shared__ u16 As[64 * 64];
    __shared__ u16 Bs[64 * 64];

    const f32x4 vzero = {0.f, 0.f, 0.f, 0.f};
    f32x4 acc[2][2];
#pragma unroll
    for (int i = 0; i < 2; ++i)
#pragma unroll
        for (int j = 0; j < 2; ++j) acc[i][j] = vzero;

    for (int k0 = 0; k0 < K; k0 += 64) {
#pragma unroll
        for (int i = 0; i < 2; ++i) {
            int c = tid + i * 256;
            int row = c >> 3, pc = c & 7, lc = pc ^ (row & 7);
            // wave-uniform LDS base: chunk (i*256 + wave*64); HW adds lane*16
            gload_lds16(A + (long long)(m0 + row) * aStride + (k0 + lc * 8),
                        &As[(i * 256 + wave * 64) * 8]);
            gload_lds16(Bt + (long long)(n0 + row) * bStride + (k0 + lc * 8),
                        &Bs[(i * 256 + wave * 64) * 8]);
        }
        __syncthreads();   // vmcnt(0) drain before s_barrier completes the DMA
        __builtin_amdgcn_s_setprio(1);
#pragma unroll
        for (int ks = 0; ks < 2; ++ks) {
            bf16x8 af[2], bfr[2];
#pragma unroll
            for (int mi = 0; mi < 2; ++mi) {
                int row = wm * 32 + mi * 16 + l16;
                int pc = ((ks << 2) | quad) ^ (row & 7);
                af[mi] = *(const bf16x8*)&As[row * 64 + pc * 8];
            }
#pragma unroll
            for (int ni = 0; ni < 2; ++ni) {
                int row = wn * 32 + ni * 16 + l16;
                int pc = ((ks << 2) | quad) ^ (row & 7);
                bfr[ni] = *(const bf16x8*)&Bs[row * 64 + pc * 8];
            }
#pragma unroll
            for (int mi = 0; mi < 2; ++mi)
#pragma unroll
                for (int ni = 0; ni < 2; ++ni)
                    acc[mi][ni] = __builtin_amdgcn_mfma_f32_16x16x32_bf16(
                        bfr[ni], af[mi], acc[mi][ni], 0, 0, 0);
        }
        __builtin_amdgcn_s_setprio(0);
        __syncthreads();
    }

#pragma unroll
    for (int mi = 0; mi < 2; ++mi) {
        int row = m0 + wm * 32 + mi * 16 + l16;
#pragma unroll
        for (int ni = 0; ni < 2; ++ni) {
            int colb = n0 + wn * 32 + ni * 16 + quad * 4;
            u16 pk[4];
#pragma unroll
            for (int r = 0; r < 4; ++r) {
                float v = acc[mi][ni][r] + bias[colb + r];
                if (EPI == 1) v = v > 0.f ? v : 0.f;
                if (EPI == 3) { if (colb + r < 512) v *= epiScale; }
                pk[r] = f2b(v);
            }
            uint2 p;
            p.x = (uint32_t)pk[0] | ((uint32_t)pk[1] << 16);
            p.y = (uint32_t)pk[2] | ((uint32_t)pk[3] << 16);
            *(uint2*)(out + (long long)row * oStride + colb) = p;
        }
    }
}

// ---------------------------------------------------------------------------
// bandg[(t*8 + h)*9 + e] = q~[t,h,:] . erk[e,:]  (q pre-scaled by log2e/8)
// ---------------------------------------------------------------------------
__global__ __launch_bounds__(256) void bandg_k(
    const u16* __restrict__ qkv, const float* __restrict__ erk,
    float* __restrict__ bandg)
{
    __shared__ float erkS[576];
    const int tid = threadIdx.x;
    for (int idx = tid; idx < 576; idx += 256) erkS[idx] = erk[idx];
    __syncthreads();
    const int gid = blockIdx.x * 256 + tid;       // 49152
    const int row = gid >> 3, h = gid & 7;
    const u16* q = qkv + (long long)row * 1536 + h * 64;
    float acc[9];
#pragma unroll
    for (int e = 0; e < 9; ++e) acc[e] = 0.f;
#pragma unroll
    for (int c = 0; c < 8; ++c) {
        uint4 d4 = *(const uint4*)(q + c * 8);
        const uint32_t dw[4] = {d4.x, d4.y, d4.z, d4.w};
#pragma unroll
        for (int j = 0; j < 8; ++j) {
            u16 uu = (u16)((dw[j >> 1] >> ((j & 1) * 16)) & 0xffff);
            float qv = b2f(uu);
            int d = c * 8 + j;
#pragma unroll
            for (int e = 0; e < 9; ++e) acc[e] += qv * erkS[e * 64 + d];
        }
    }
    float* o = bandg + (long long)gid * 9;
#pragma unroll
    for (int e = 0; e < 9; ++e) o[e] = acc[e];
}

// ---------------------------------------------------------------------------
// Flash attention (R14-exact, verified 46us): 32 q-rows / 2 waves per block;
// single-buffered K/V; LDS ~25.5 KB -> 6 blocks/CU; grid 24x64 = 1536 blocks
// (XCD-swizzled, bijective). exp2 domain, tree-max, native bf16 pack.
// ---------------------------------------------------------------------------
__global__ __launch_bounds__(128) void flash_attn(
    const u16* __restrict__ qkv, const u16* __restrict__ vt,
    const float* __restrict__ mask, const float* __restrict__ bandg,
    const float* __restrict__ erv, u16* __restrict__ outb)
{
    const int tid = threadIdx.x;           // 0..127
    const int w = tid >> 6, lane = tid & 63;
    const int quad = lane >> 4, l16 = lane & 15;
    const int orig = blockIdx.y * 24 + blockIdx.x;
    const int swz = (orig & 7) * 192 + (orig >> 3);
    const int qt = swz % 24, bh = swz / 24;
    const int b = bh >> 3, h = bh & 7;
    const int q0 = qt * 32;

    __shared__ u16 Ql[32 * 64];        //  4 KB
    __shared__ u16 Kt[64 * 64];        //  8 KB
    __shared__ u16 Vt[64 * 64];        //  8 KB
    __shared__ u16 Pl[2][16 * 64];     //  4 KB
    __shared__ float bandk[32][10];    //  1.25 KB
    __shared__ float maskK[64];        //  256 B

    // Q stage: 32*64 u16 = 256 chunks / 128 threads = 2 each
#pragma unroll
    for (int i = 0; i < 2; ++i) {
        int c = tid + i * 128;
        int r = c >> 3, pc = c & 7, lc = pc ^ (r & 7);
        *(uint4*)&Ql[c * 8] =
            *(const uint4*)(qkv + (long long)(b * T_ + q0 + r) * 1536 + h * 64 + lc * 8);
    }
    for (int idx = tid; idx < 288; idx += 128) {
        int r = idx / 9, e = idx - r * 9;
        bandk[r][e] = bandg[((long long)(b * T_ + q0 + r) * 8 + h) * 9 + e];
    }

    const int i_row = q0 + w * 16 + l16;
    const float mi = mask[b * T_ + i_row];
    float m_run = -1e30f, l_run = 0.f;
    const f32x4 vzero = {0.f, 0.f, 0.f, 0.f};
    f32x4 vacc[4] = {vzero, vzero, vzero, vzero};
    float pb[3] = {0.f, 0.f, 0.f};

    __syncthreads();
    bf16x8 qf[2];
#pragma unroll
    for (int ks = 0; ks < 2; ++ks) {
        int r = w * 16 + l16;
        int pc = ((ks << 2) | quad) ^ (r & 7);
        qf[ks] = *(const bf16x8*)&Ql[r * 64 + pc * 8];
    }

    for (int kt = 0; kt < 12; ++kt) {
        __syncthreads();   // all waves done reading Kt/Vt from previous iter
        // K/V stage: 64*64 u16 = 512 chunks each / 128 threads = 4 each
#pragma unroll
        for (int i = 0; i < 4; ++i) {
            int c = tid + i * 128;
            int r = c >> 3, pc = c & 7, lc = pc ^ (r & 7);
            *(uint4*)&Kt[c * 8] =
                *(const uint4*)(qkv + (long long)(b * T_ + kt * 64 + r) * 1536 + 512 + h * 64 + lc * 8);
            *(uint4*)&Vt[c * 8] =
                *(const uint4*)(vt + ((long long)bh * 64 + r) * T_ + kt * 64 + lc * 8);
        }
        if (tid < 64) maskK[tid] = mask[b * T_ + kt * 64 + tid];
        __syncthreads();

        const float mkv = maskK[lane];
        const bool tile_clean = (__ballot(mkv == 0.f) == 0ull);
        const bool fast = tile_clean && (mi != 0.f);
        const bool has_band = (kt * 64 <= q0 + w * 16 + 19) &&
                              (kt * 64 + 67 >= q0 + w * 16);

        f32x4 sacc[4];
#pragma unroll
        for (int ni = 0; ni < 4; ++ni) sacc[ni] = vzero;
        __builtin_amdgcn_s_setprio(1);
#pragma unroll
        for (int ks = 0; ks < 2; ++ks)
#pragma unroll
            for (int ni = 0; ni < 4; ++ni) {
                int r = ni * 16 + l16;
                int pc = ((ks << 2) | quad) ^ (r & 7);
                bf16x8 kf = *(const bf16x8*)&Kt[r * 64 + pc * 8];
                sacc[ni] = __builtin_amdgcn_mfma_f32_16x16x32_bf16(kf, qf[ks], sacc[ni], 0, 0, 0);
            }
        __builtin_amdgcn_s_setprio(0);

        if (has_band) {
#pragma unroll
            for (int ni = 0; ni < 4; ++ni)
#pragma unroll
                for (int r = 0; r < 4; ++r) {
                    int jl = ni * 16 + quad * 4 + r;
                    int dlt = kt * 64 + jl - i_row;
                    if (dlt >= -4 && dlt <= 4)
                        sacc[ni][r] += bandk[w * 16 + l16][dlt + 4];
                }
        }
        if (!fast) {
#pragma unroll
            for (int ni = 0; ni < 4; ++ni)
#pragma unroll
                for (int r = 0; r < 4; ++r) {
                    int jl = ni * 16 + quad * 4 + r;
                    if (mi * maskK[jl] == 0.f) sacc[ni][r] = -14427.0f;  // -1e4*log2e
                }
        }

        // row max: pairwise tree
        float mx;
        {
            float a0 = fmaxf(sacc[0][0], sacc[0][1]), a1 = fmaxf(sacc[0][2], sacc[0][3]);
            float b0 = fmaxf(sacc[1][0], sacc[1][1]), b1 = fmaxf(sacc[1][2], sacc[1][3]);
            float c0 = fmaxf(sacc[2][0], sacc[2][1]), c1 = fmaxf(sacc[2][2], sacc[2][3]);
            float d0 = fmaxf(sacc[3][0], sacc[3][1]), d1 = fmaxf(sacc[3][2], sacc[3][3]);
            float t0 = fmaxf(fmaxf(a0, a1), fmaxf(b0, b1));
            float t1 = fmaxf(fmaxf(c0, c1), fmaxf(d0, d1));
            mx = fmaxf(t0, t1);
        }
        mx = fmaxf(mx, __shfl_xor(mx, 16));
        mx = fmaxf(mx, __shfl_xor(mx, 32));
        const float m_new = fmaxf(m_run, mx);
        const float alpha = exp2f(m_run - m_new);
        m_run = m_new;
        l_run *= alpha;
#pragma unroll
        for (int ni = 0; ni < 4; ++ni) vacc[ni] = vacc[ni] * alpha;
#pragma unroll
        for (int k = 0; k < 3; ++k) pb[k] *= alpha;

        // exp2 + native-pack P tile
        float lsum = 0.f;
#pragma unroll
        for (int ni = 0; ni < 4; ++ni) {
            float u0 = exp2f(sacc[ni][0] - m_new);
            float u1 = exp2f(sacc[ni][1] - m_new);
            float u2 = exp2f(sacc[ni][2] - m_new);
            float u3 = exp2f(sacc[ni][3] - m_new);
            lsum += (u0 + u1) + (u2 + u3);
            union { __bf16 hh[2]; uint32_t u; } cA, cB;
            cA.hh[0] = (__bf16)u0; cA.hh[1] = (__bf16)u1;
            cB.hh[0] = (__bf16)u2; cB.hh[1] = (__bf16)u3;
            int c0 = ni * 16 + quad * 4;
            int phys = (((c0 >> 3) ^ (l16 & 7)) << 3) + (c0 & 7);
            uint2 p; p.x = cA.u; p.y = cB.u;
            *(uint2*)&Pl[w][l16 * 64 + phys] = p;
        }
        l_run += lsum;

        if (has_band) {
#pragma unroll
            for (int k = 0; k < 3; ++k) {
                int e = quad * 3 + k;
                if (e < 9) {
                    int jl = i_row + e - 4 - kt * 64;
                    if (jl >= 0 && jl < 64) {
                        int phys = (((jl >> 3) ^ (l16 & 7)) << 3) + (jl & 7);
                        pb[k] += b2f(Pl[w][l16 * 64 + phys]);
                    }
                }
            }
        }

        __builtin_amdgcn_s_setprio(1);
#pragma unroll
        for (int ks = 0; ks < 2; ++ks) {
            int pcc = ((ks << 2) | quad) ^ (l16 & 7);
            bf16x8 pf = *(const bf16x8*)&Pl[w][l16 * 64 + pcc * 8];
#pragma unroll
            for (int ni = 0; ni < 4; ++ni) {
                int r = ni * 16 + l16;
                int pc = ((ks << 2) | quad) ^ (r & 7);
                bf16x8 vf = *(const bf16x8*)&Vt[r * 64 + pc * 8];
                vacc[ni] = __builtin_amdgcn_mfma_f32_16x16x32_bf16(vf, pf, vacc[ni], 0, 0, 0);
            }
        }
        __builtin_amdgcn_s_setprio(0);
    }

    l_run += __shfl_xor(l_run, 16);
    l_run += __shfl_xor(l_run, 32);
    const float rinv = 1.f / l_run;

    float pband[9];
#pragma unroll
    for (int e = 0; e < 9; ++e) {
        float val = (quad == e / 3) ? pb[e % 3] : 0.f;
        val += __shfl_xor(val, 16);
        val += __shfl_xor(val, 32);
        pband[e] = val * rinv;
    }

    u16* orow = outb + (long long)(b * T_ + i_row) * C_ + h * 64;
#pragma unroll
    for (int ni = 0; ni < 4; ++ni) {
        u16 pk[4];
#pragma unroll
        for (int r = 0; r < 4; ++r) {
            int d = ni * 16 + quad * 4 + r;
            float v = vacc[ni][r] * rinv;
#pragma unroll
            for (int e = 0; e < 9; ++e) v += pband[e] * erv[e * 64 + d];
            pk[r] = f2b(v);
        }
        uint2 p;
        p.x = (uint32_t)pk[0] | ((uint32_t)pk[1] << 16);
        p.y = (uint32_t)pk[2] | ((uint32_t)pk[3] << 16);
        *(uint2*)(orow + ni * 16 + quad * 4) = p;
    }
}

// ---------------------------------------------------------------------------
// One-time weight transposes (f32 -> bf16), batched over layers.
// ---------------------------------------------------------------------------
__global__ void transpose_qkvo(const float* __restrict__ Wq, const float* __restrict__ Wk,
                               const float* __restrict__ Wv, const float* __restrict__ Wo,
                               u16* __restrict__ wqkvT, u16* __restrict__ woT)
{
    __shared__ u16 tile[32][33];
    const int z = blockIdx.z, l = z >> 2, which = z & 3;
    const float* src = (which == 0 ? Wq : which == 1 ? Wk : which == 2 ? Wv : Wo)
                       + (long long)l * 262144;
    u16* dst = (which == 3) ? woT + (long long)l * 262144
                            : wqkvT + (long long)l * 786432 + which * 262144;
    const int r0 = blockIdx.y * 32, c0 = blockIdx.x * 32;
    const int tx = threadIdx.x, ty = threadIdx.y;
#pragma unroll
    for (int i = 0; i < 32; i += 8)
        tile[ty + i][tx] = f2b(src[(long long)(r0 + ty + i) * 512 + (c0 + tx)]);
    __syncthreads();
#pragma unroll
    for (int i = 0; i < 32; i += 8)
        dst[(long long)(c0 + ty + i) * 512 + (r0 + tx)] = tile[tx][ty + i];
}

__global__ void transpose_f2bL(const float* __restrict__ src0, int sStride, long long sLayer,
                               u16* __restrict__ dst0, int dStride, long long dLayer)
{
    __shared__ u16 tile[32][33];
    const int l = blockIdx.z;
    const float* src = src0 + (long long)l * sLayer;
    u16* dst = dst0 + (long long)l * dLayer;
    const int r0 = blockIdx.y * 32, c0 = blockIdx.x * 32;
    const int tx = threadIdx.x, ty = threadIdx.y;
#pragma unroll
    for (int i = 0; i < 32; i += 8)
        tile[ty + i][tx] = f2b(src[(long long)(r0 + ty + i) * sStride + (c0 + tx)]);
    __syncthreads();
#pragma unroll
    for (int i = 0; i < 32; i += 8)
        dst[(long long)(c0 + ty + i) * dStride + (r0 + tx)] = tile[tx][ty + i];
}

__global__ void transpose_b(const u16* __restrict__ src, long long sB1, long long sB2, int sStride,
                            u16* __restrict__ dst, long long dB1, long long dB2, int dStride)
{
    __shared__ u16 tile[32][33];
    const int z = blockIdx.z, zb = z >> 3, zh = z & 7;
    src += (long long)zb * sB1 + (long long)zh * sB2;
    dst += (long long)zb * dB1 + (long long)zh * dB2;
    const int r0 = blockIdx.y * 32, c0 = blockIdx.x * 32;
    const int tx = threadIdx.x, ty = threadIdx.y;
#pragma unroll
    for (int i = 0; i < 32; i += 8)
        tile[ty + i][tx] = src[(long long)(r0 + ty + i) * sStride + (c0 + tx)];
    __syncthreads();
#pragma unroll
    for (int i = 0; i < 32; i += 8)
        dst[(long long)(c0 + ty + i) * dStride + (r0 + tx)] = tile[tx][ty + i];
}

__global__ void concat_bias(const float* __restrict__ bq, const float* __restrict__ bk,
                            const float* __restrict__ bv, float* __restrict__ dst)
{
    int i = blockIdx.x * 256 + threadIdx.x;
    int l = i / 1536, n = i - l * 1536;
    float v = (n < 512) ? bq[l * 512 + n]
             : (n < 1024 ? bk[l * 512 + (n - 512)] : bv[l * 512 + (n - 1024)]);
    dst[i] = v;
}

__global__ void mask_in(const float* __restrict__ x, const float* __restrict__ mask,
                        u16* __restrict__ out)
{
    int i4 = (blockIdx.x * 256 + threadIdx.x) * 4;
    float4 xv = *(const float4*)(x + i4);
    float m = mask[i4 >> 9];
    u16 pk[4] = {f2b(xv.x * m), f2b(xv.y * m), f2b(xv.z * m), f2b(xv.w * m)};
    uint2 p; p.x = (uint32_t)pk[0] | ((uint32_t)pk[1] << 16);
    p.y = (uint32_t)pk[2] | ((uint32_t)pk[3] << 16);
    *(uint2*)(out + i4) = p;
}

__global__ void mask_out(const u16* __restrict__ x, const float* __restrict__ mask,
                         float* __restrict__ out)
{
    int i4 = (blockIdx.x * 256 + threadIdx.x) * 4;
    uint2 p = *(const uint2*)(x + i4);
    float m = mask[i4 >> 9];
    float4 o;
    o.x = b2f((u16)(p.x & 0xffff)) * m;
    o.y = b2f((u16)(p.x >> 16)) * m;
    o.z = b2f((u16)(p.y & 0xffff)) * m;
    o.w = b2f((u16)(p.y >> 16)) * m;
    *(float4*)(out + i4) = o;
}

__global__ __launch_bounds__(256) void add_ln(
    const u16* __restrict__ x, const u16* __restrict__ y,
    const float* __restrict__ sc, const float* __restrict__ bi,
    u16* __restrict__ outx)
{
    const int wave = threadIdx.x >> 6, lane = threadIdx.x & 63;
    const long long r = (long long)blockIdx.x * 4 + wave;
    const u16* xr = x + r * C_;
    const u16* yr = y + r * C_;
    float v[8], s = 0.f;
#pragma unroll
    for (int it = 0; it < 2; ++it) {
        int j0 = it * 256 + lane * 4;
        uint2 px = *(const uint2*)(xr + j0);
        uint2 py = *(const uint2*)(yr + j0);
        v[it * 4 + 0] = b2f((u16)(px.x & 0xffff)) + b2f((u16)(py.x & 0xffff));
        v[it * 4 + 1] = b2f((u16)(px.x >> 16))    + b2f((u16)(py.x >> 16));
        v[it * 4 + 2] = b2f((u16)(px.y & 0xffff)) + b2f((u16)(py.y & 0xffff));
        v[it * 4 + 3] = b2f((u16)(px.y >> 16))    + b2f((u16)(py.y >> 16));
        s += v[it * 4 + 0] + v[it * 4 + 1] + v[it * 4 + 2] + v[it * 4 + 3];
    }
#pragma unroll
    for (int off = 32; off > 0; off >>= 1) s += __shfl_down(s, off);
    s = __shfl(s, 0);
    const float mean = s * (1.f / 512.f);
    float var = 0.f;
#pragma unroll
    for (int l = 0; l < 8; ++l) { float d = v[l] - mean; var += d * d; }
#pragma unroll
    for (int off = 32; off > 0; off >>= 1) var += __shfl_down(var, off);
    var = __shfl(var, 0);
    const float rs = rsqrtf(var * (1.f / 512.f) + 1e-6f);
    u16* orow = outx + r * C_;
#pragma unroll
    for (int it = 0; it < 2; ++it) {
        int j0 = it * 256 + lane * 4;
        float4 s4 = *(const float4*)(sc + j0);
        float4 b4 = *(const float4*)(bi + j0);
        u16 pk[4];
        pk[0] = f2b((v[it * 4 + 0] - mean) * rs * s4.x + b4.x);
        pk[1] = f2b((v[it * 4 + 1] - mean) * rs * s4.y + b4.y);
        pk[2] = f2b((v[it * 4 + 2] - mean) * rs * s4.z + b4.z);
        pk[3] = f2b((v[it * 4 + 3] - mean) * rs * s4.w + b4.w);
        uint2 p; p.x = (uint32_t)pk[0] | ((uint32_t)pk[1] << 16);
        p.y = (uint32_t)pk[2] | ((uint32_t)pk[3] << 16);
        *(uint2*)(orow + j0) = p;
    }
}

// ===========================================================================
extern "C" void kernel_launch(void* const* d_in, const int* in_sizes, int n_in,
                              void* d_out, int out_size, void* d_ws, size_t ws_size,
                              hipStream_t stream)
{
    const float* x    = (const float*)d_in[0];
    const float* mask = (const float*)d_in[1];
    const float* Wq   = (const float*)d_in[2];
    const float* bq   = (const float*)d_in[3];
    const float* Wk   = (const float*)d_in[4];
    const float* bk   = (const float*)d_in[5];
    const float* Wv   = (const float*)d_in[6];
    const float* bv   = (const float*)d_in[7];
    const float* Wo   = (const float*)d_in[8];
    const float* bo   = (const float*)d_in[9];
    const float* erk  = (const float*)d_in[10];
    const float* erv  = (const float*)d_in[11];
    const float* ln1s = (const float*)d_in[12];
    const float* ln1b = (const float*)d_in[13];
    const float* W1   = (const float*)d_in[14];
    const float* b1   = (const float*)d_in[15];
    const float* W2   = (const float*)d_in[16];
    const float* b2   = (const float*)d_in[17];
    const float* ln2s = (const float*)d_in[18];
    const float* ln2b = (const float*)d_in[19];
    float* out = (float*)d_out;
    u16* ws  = (u16*)d_ws;

    const long long CF = 512LL * 2048;
    const int M = B_ * T_;  // 6144

    // ws layout (u16 units). Total 51,234,816 u16 = 102.5 MB (<121.7 MB proven).
    u16* wqkvT   = ws;                      // [6][1536][512]
    u16* woT     = ws + 4718592;            // [6][512][512]
    u16* w1T     = ws + 6291456;            // [6][2048][512]
    u16* w2T     = ws + 12582912;           // [6][512][2048]
    float* bqkv  = (float*)(ws + 18874368); // [6][1536] f32
    u16* xb      = ws + 18892800;           // [M][512]
    u16* qkvb    = ws + 22038528;           // [M][1536]
    u16* vtb     = ws + 31475712;           // [64][64][768]; aliased as yb
    u16* attnb   = ws + 34621440;           // [M][512]
    u16* scr     = ws + 37767168;           // h1 [M][2048]
    float* bandg = (float*)(ws + 50350080); // [M][8][9] f32
    u16* yb      = vtb;

    const dim3 tb(32, 8);

    // --- one-time prologue ---
    transpose_qkvo<<<dim3(16, 16, 24), tb, 0, stream>>>(Wq, Wk, Wv, Wo, wqkvT, woT);
    transpose_f2bL<<<dim3(64, 16, 6), tb, 0, stream>>>(W1, 2048, CF, w1T, 512, 1048576);
    transpose_f2bL<<<dim3(16, 64, 6), tb, 0, stream>>>(W2, 512,  CF, w2T, 2048, 1048576);
    concat_bias<<<36, 256, 0, stream>>>(bq, bk, bv, bqkv);
    mask_in<<<(M * 512) / 1024, 256, 0, stream>>>(x, mask, xb);

    for (int l = 0; l < 6; ++l) {
        // QKV: [6144,512] @ [1536,512]^T; q *= log2e/8 in epilogue (cols<512)
        gemm_bt4<3><<<dim3(96, 24), 256, 0, stream>>>(
            xb, 512, wqkvT + (long long)l * 786432, 512, bqkv + l * 1536,
            qkvb, 1536, 512, 0.125f * LOG2E);
        // bandk table for this layer
        bandg_k<<<192, 256, 0, stream>>>(qkvb, erk + l * 576, bandg);
        // V^T per head: [64][768]
        transpose_b<<<dim3(2, 24, 64), tb, 0, stream>>>(
            qkvb + 1024, 768LL * 1536, 64, 1536,
            vtb, 8LL * 64 * 768, 64LL * 768, 768);
        // fused attention -> attnb (1536 blocks x 2 waves)
        flash_attn<<<dim3(24, 64), 128, 0, stream>>>(
            qkvb, vtb, mask, bandg, erv + l * 576, attnb);
        // O projection -> yb (=vtb, dead now)
        gemm_bt4<0><<<dim3(96, 8), 256, 0, stream>>>(
            attnb, 512, woT + (long long)l * 262144, 512, bo + l * 512,
            yb, 512, 512, 0.f);
        add_ln<<<1536, 256, 0, stream>>>(xb, yb, ln1s + l * 512, ln1b + l * 512, xb);
        // FFN1 (relu fused)
        gemm_bt4<1><<<dim3(96, 32), 256, 0, stream>>>(
            xb, 512, w1T + (long long)l * 1048576, 512, b1 + l * 2048,
            scr, 2048, 512, 0.f);
        // FFN2
        gemm_bt4<0><<<dim3(96, 8), 256, 0, stream>>>(
            scr, 2048, w2T + (long long)l * 1048576, 2048, b2 + l * 512,
            yb, 512, 2048, 0.f);
        add_ln<<<1536, 256, 0, stream>>>(xb, yb, ln2s + l * 512, ln2b + l * 512, xb);
    }

    mask_out<<<(M * 512) / 1024, 256, 0, stream>>>(xb, mask, out);
}